// Round 11
// baseline (633.788 us; speedup 1.0000x reference)
//
#include <hip/hip_runtime.h>
#include <hip/hip_bf16.h>
#include <math.h>

#define NTOK 4096
#define CH 512
#define CQD 64
#define NBATCH 4

typedef __bf16 bf16x8 __attribute__((ext_vector_type(8)));
typedef float f32x4 __attribute__((ext_vector_type(4)));
typedef unsigned int u32x4 __attribute__((ext_vector_type(4)));
typedef unsigned short u16x4 __attribute__((ext_vector_type(4)));

__device__ __forceinline__ unsigned short f2bf(float f) {
  unsigned int u = __builtin_bit_cast(unsigned int, f);
  unsigned int r = (u + 0x7FFFu + ((u >> 16) & 1u)) >> 16;
  return (unsigned short)r;
}

__device__ __forceinline__ bf16x8 load_frag(const unsigned short* p) {
  u32x4 v = *reinterpret_cast<const u32x4*>(p);
  return __builtin_bit_cast(bf16x8, v);
}

// ---- K0a: transpose + convert x -> xT bf16 (B, N, 1024): [0..511]=xs, [512..1023]=xt
__global__ void k_transpose(const float* __restrict__ xs, const float* __restrict__ xt,
                            unsigned short* __restrict__ xT) {
  __shared__ unsigned short lds[64][66];
  int b = blockIdx.z;
  int n0 = blockIdx.x * 64;
  int c0 = blockIdx.y * 64;  // 0..1023
  const float* src = (c0 < CH) ? xs : xt;
  int cs0 = (c0 < CH) ? c0 : c0 - CH;
  int tid = threadIdx.x;
  int nn = tid & 63, cg = tid >> 6;
  const float* base = src + ((size_t)b * CH + cs0) * NTOK + n0;
  for (int cc = cg; cc < 64; cc += 4)
    lds[cc][nn] = f2bf(base[(size_t)cc * NTOK + nn]);
  __syncthreads();
  int cw = tid & 63, ng = tid >> 6;
  unsigned short* dst = xT + ((size_t)b * NTOK + n0) * 1024 + c0 + cw;
  for (int n2 = ng; n2 < 64; n2 += 4)
    dst[(size_t)n2 * 1024] = lds[cw][n2];
}

// ---- K0b: weights f32 -> bf16 (Wq, Wk, Wv = [Wvs | Wvt])
__global__ void k_weights(const float* __restrict__ Wq, const float* __restrict__ Wk,
                          const float* __restrict__ Wvs, const float* __restrict__ Wvt,
                          unsigned short* __restrict__ wq, unsigned short* __restrict__ wk,
                          unsigned short* __restrict__ wv) {
  int t = blockIdx.x * 256 + threadIdx.x;
  if (t < 32768) {
    wq[t] = f2bf(Wq[t]);
  } else if (t < 65536) {
    int j = t - 32768;
    wk[j] = f2bf(Wk[j]);
  } else {
    int j = t - 65536;
    if (j < 512 * 1024) {
      int c = j >> 10, k = j & 1023;
      float v = (k < 512) ? Wvs[c * 512 + k] : Wvt[c * 512 + (k - 512)];
      wv[j] = f2bf(v);
    }
  }
}

// ---- K1: projection GEMM. D[n][m] = sum_k xT[b][n][koff+k] * W[m][k] (+bias)
// mode 0: out[b][n][m] (N x 64) scalar bf16 stores (for Q, Kt)
// mode 1: out[b][m][n] (C x N) packed 4-wide bf16 stores (for V)
__global__ void __launch_bounds__(256)
k_proj(const unsigned short* __restrict__ xT, const unsigned short* __restrict__ W,
       const float* __restrict__ bias1, const float* __restrict__ bias2,
       unsigned short* __restrict__ out, int Kdim, int koff, int mode) {
  int b = blockIdx.z;
  int n0 = blockIdx.x * 256;
  int m0 = blockIdx.y * 64;
  int tid = threadIdx.x;
  int w = tid >> 6, l = tid & 63;
  int fr = l & 15, fk = l >> 4;
  f32x4 acc[4][4] = {};  // [nstrip][mfrag]
  const unsigned short* xbase =
      xT + ((size_t)b * NTOK + n0 + w * 64 + fr) * 1024 + koff + fk * 8;
  const unsigned short* wbase = W + ((size_t)(m0 + fr)) * Kdim + fk * 8;
  for (int k = 0; k < Kdim; k += 32) {
    bf16x8 a[4], bb[4];
#pragma unroll
    for (int ns = 0; ns < 4; ns++) a[ns] = load_frag(xbase + (size_t)ns * 16 * 1024 + k);
#pragma unroll
    for (int mf = 0; mf < 4; mf++) bb[mf] = load_frag(wbase + (size_t)mf * 16 * Kdim + k);
#pragma unroll
    for (int ns = 0; ns < 4; ns++)
#pragma unroll
      for (int mf = 0; mf < 4; mf++)
        acc[ns][mf] = __builtin_amdgcn_mfma_f32_16x16x32_bf16(a[ns], bb[mf], acc[ns][mf], 0, 0, 0);
  }
  if (mode == 0) {
#pragma unroll
    for (int ns = 0; ns < 4; ns++)
#pragma unroll
      for (int mf = 0; mf < 4; mf++) {
        int m = m0 + mf * 16 + fr;
        float bv = bias1[m];
        int nb = n0 + w * 64 + ns * 16 + fk * 4;
#pragma unroll
        for (int r = 0; r < 4; r++)
          out[((size_t)b * NTOK + nb + r) * CQD + m] = f2bf(acc[ns][mf][r] + bv);
      }
  } else {
#pragma unroll
    for (int ns = 0; ns < 4; ns++)
#pragma unroll
      for (int mf = 0; mf < 4; mf++) {
        int c = m0 + mf * 16 + fr;
        float bv = bias1[c] + bias2[c];
        int nb = n0 + w * 64 + ns * 16 + fk * 4;
        u16x4 pk;
#pragma unroll
        for (int r = 0; r < 4; r++) pk[r] = f2bf(acc[ns][mf][r] + bv);
        *reinterpret_cast<u16x4*>(out + ((size_t)b * CH + c) * NTOK + nb) = pk;
      }
  }
}

// ---- K2a: QK -> P = exp(0.125*S - 8) bf16 [z][i][j] + row sums (atomic).
// Swapped MFMA (R5-verified): A=Kt rows (j), B=Q rows (i); lane holds 4 consecutive
// j for fixed i -> u16x4 global store, j-contiguous. No LDS, no barriers.
// Block 256 = 4 waves; wave = 64 i x 64 j. P indexed by blockIdx.z (chunk-local).
__global__ void __launch_bounds__(256)
k_qk(const unsigned short* __restrict__ Q, const unsigned short* __restrict__ Kt,
     unsigned short* __restrict__ P, float* __restrict__ rsum, int b0) {
  int zb = blockIdx.z;
  int b = b0 + zb;
  int i0 = blockIdx.y * 64;
  int w = threadIdx.x >> 6;
  int j0 = blockIdx.x * 256 + w * 64;
  int l = threadIdx.x & 63, fr = l & 15, fk = l >> 4;

  bf16x8 qf[4][2];
#pragma unroll
  for (int f = 0; f < 4; f++) {
    const unsigned short* qb = Q + ((size_t)b * NTOK + i0 + f * 16 + fr) * CQD + fk * 8;
    qf[f][0] = load_frag(qb);
    qf[f][1] = load_frag(qb + 32);
  }
  float dsum[4] = {0.f, 0.f, 0.f, 0.f};
  const unsigned short* kb = Kt + ((size_t)b * NTOK + j0 + fr) * CQD + fk * 8;

#pragma unroll
  for (int jf = 0; jf < 4; jf++) {
    bf16x8 k0 = load_frag(kb + (size_t)jf * 16 * CQD);
    bf16x8 k1 = load_frag(kb + (size_t)jf * 16 * CQD + 32);
#pragma unroll
    for (int f = 0; f < 4; f++) {
      f32x4 s = {};
      s = __builtin_amdgcn_mfma_f32_16x16x32_bf16(k0, qf[f][0], s, 0, 0, 0);
      s = __builtin_amdgcn_mfma_f32_16x16x32_bf16(k1, qf[f][1], s, 0, 0, 0);
      u16x4 pk;
#pragma unroll
      for (int r = 0; r < 4; r++) {
        float p = __expf(0.125f * s[r] - 8.0f);
        dsum[f] += p;
        pk[r] = f2bf(p);
      }
      // i = i0+f*16+fr (D col), j = j0 + jf*16 + fk*4 + r (D row)
      *reinterpret_cast<u16x4*>(P + ((size_t)zb * NTOK + i0 + f * 16 + fr) * NTOK + j0 +
                                jf * 16 + fk * 4) = pk;
    }
  }
#pragma unroll
  for (int f = 0; f < 4; f++) {
    float v = dsum[f];
    v += __shfl_xor(v, 16);
    v += __shfl_xor(v, 32);
    if (l < 16) atomicAdd(&rsum[(size_t)b * NTOK + i0 + f * 16 + l], v);
  }
}

// ---- K2b: out[c][i] = (sum_j U[c][j] * P[i][j]) / rsum[i] + xs + xt.
// k_proj-verified no-LDS GEMM pattern: A = P rows (i), B = U rows (c), K=j=4096.
// Block 256 = 4 waves, tile 128i x 32c; wave = 32i x 32c. Zero barriers, pure TLP.
__global__ void __launch_bounds__(256)
k_pv2(const unsigned short* __restrict__ P, const unsigned short* __restrict__ U,
      const float* __restrict__ rsum, const float* __restrict__ xs,
      const float* __restrict__ xt, float* __restrict__ out, int b0) {
  int zb = blockIdx.z;
  int b = b0 + zb;
  int c0 = blockIdx.x * 32;
  int w = threadIdx.x >> 6;
  int i0 = blockIdx.y * 128 + w * 32;
  int l = threadIdx.x & 63, fr = l & 15, fk = l >> 4;

  f32x4 acc[2][2] = {};  // [is][cf]
  const unsigned short* pbase = P + ((size_t)zb * NTOK + i0 + fr) * NTOK + fk * 8;
  const unsigned short* ubase = U + ((size_t)b * CH + c0 + fr) * NTOK + fk * 8;

  for (int j = 0; j < NTOK; j += 64) {
    bf16x8 af[2][2], bf[2][2];
#pragma unroll
    for (int is = 0; is < 2; is++) {
      af[is][0] = load_frag(pbase + (size_t)is * 16 * NTOK + j);
      af[is][1] = load_frag(pbase + (size_t)is * 16 * NTOK + j + 32);
    }
#pragma unroll
    for (int cf = 0; cf < 2; cf++) {
      bf[cf][0] = load_frag(ubase + (size_t)cf * 16 * NTOK + j);
      bf[cf][1] = load_frag(ubase + (size_t)cf * 16 * NTOK + j + 32);
    }
#pragma unroll
    for (int is = 0; is < 2; is++)
#pragma unroll
      for (int cf = 0; cf < 2; cf++) {
        acc[is][cf] = __builtin_amdgcn_mfma_f32_16x16x32_bf16(af[is][0], bf[cf][0],
                                                              acc[is][cf], 0, 0, 0);
        acc[is][cf] = __builtin_amdgcn_mfma_f32_16x16x32_bf16(af[is][1], bf[cf][1],
                                                              acc[is][cf], 0, 0, 0);
      }
  }

  // epilogue: D row = i (fk*4+r), col = c (fr)
  f32x4 rden[2];
#pragma unroll
  for (int is = 0; is < 2; is++) {
    f32x4 rs = *reinterpret_cast<const f32x4*>(rsum + (size_t)b * NTOK + i0 + is * 16 + fk * 4);
#pragma unroll
    for (int r = 0; r < 4; r++) rden[is][r] = 1.0f / rs[r];
  }
#pragma unroll
  for (int is = 0; is < 2; is++)
#pragma unroll
    for (int cf = 0; cf < 2; cf++) {
      int c = c0 + cf * 16 + fr;
      size_t base = ((size_t)b * CH + c) * NTOK + i0 + is * 16 + fk * 4;
      f32x4 r1 = *reinterpret_cast<const f32x4*>(xs + base);
      f32x4 r2 = *reinterpret_cast<const f32x4*>(xt + base);
      f32x4 o;
#pragma unroll
      for (int r = 0; r < 4; r++) o[r] = acc[is][cf][r] * rden[is][r] + r1[r] + r2[r];
      *reinterpret_cast<f32x4*>(out + base) = o;
    }
}

extern "C" void kernel_launch(void* const* d_in, const int* in_sizes, int n_in,
                              void* d_out, int out_size, void* d_ws, size_t ws_size,
                              hipStream_t stream) {
  const float* xs  = (const float*)d_in[0];
  const float* xt  = (const float*)d_in[1];
  const float* Wq  = (const float*)d_in[2];
  const float* bq  = (const float*)d_in[3];
  const float* Wk  = (const float*)d_in[4];
  const float* bk  = (const float*)d_in[5];
  const float* Wvs = (const float*)d_in[6];
  const float* bvs = (const float*)d_in[7];
  const float* Wvt = (const float*)d_in[8];
  const float* bvt = (const float*)d_in[9];
  float* out = (float*)d_out;

  char* ws = (char*)d_ws;
  size_t off = 0;
  unsigned short* xT = (unsigned short*)(ws + off); off += (size_t)NBATCH * NTOK * 1024 * 2;
  unsigned short* wq = (unsigned short*)(ws + off); off += (size_t)64 * 512 * 2;
  unsigned short* wk = (unsigned short*)(ws + off); off += (size_t)64 * 512 * 2;
  unsigned short* wv = (unsigned short*)(ws + off); off += (size_t)512 * 1024 * 2;
  unsigned short* Qb  = (unsigned short*)(ws + off); off += (size_t)NBATCH * NTOK * CQD * 2;
  unsigned short* Ktb = (unsigned short*)(ws + off); off += (size_t)NBATCH * NTOK * CQD * 2;
  unsigned short* Vb  = (unsigned short*)(ws + off); off += (size_t)NBATCH * CH * NTOK * 2;
  float* rsum = (float*)(ws + off); off += (size_t)NBATCH * NTOK * 4;
  unsigned short* P = (unsigned short*)(ws + off);
  size_t p_full = (size_t)NBATCH * NTOK * NTOK * 2;
  size_t p_one  = (size_t)NTOK * NTOK * 2;
  bool full = (ws_size >= off + p_full);
  if (!full && ws_size < off + p_one) return;  // insufficient scratch: fail safely

  k_transpose<<<dim3(NTOK / 64, 16, NBATCH), 256, 0, stream>>>(xs, xt, xT);
  k_weights<<<dim3(2304), 256, 0, stream>>>(Wq, Wk, Wvs, Wvt, wq, wk, wv);
  k_proj<<<dim3(NTOK / 256, 1, NBATCH), 256, 0, stream>>>(xT, wq, bq, nullptr, Qb, 512, 0, 0);
  k_proj<<<dim3(NTOK / 256, 1, NBATCH), 256, 0, stream>>>(xT, wk, bk, nullptr, Ktb, 512, 512, 0);
  k_proj<<<dim3(NTOK / 256, 8, NBATCH), 256, 0, stream>>>(xT, wv, bvs, bvt, Vb, 1024, 0, 1);
  hipMemsetAsync(rsum, 0, (size_t)NBATCH * NTOK * 4, stream);
  if (full) {
    k_qk<<<dim3(NTOK / 256, NTOK / 64, NBATCH), 256, 0, stream>>>(Qb, Ktb, P, rsum, 0);
    k_pv2<<<dim3(CH / 32, NTOK / 128, NBATCH), 256, 0, stream>>>(P, Vb, rsum, xs, xt, out, 0);
  } else {
    for (int b = 0; b < NBATCH; b++) {
      k_qk<<<dim3(NTOK / 256, NTOK / 64, 1), 256, 0, stream>>>(Qb, Ktb, P, rsum, b);
      k_pv2<<<dim3(CH / 32, NTOK / 128, 1), 256, 0, stream>>>(P, Vb, rsum, xs, xt, out, b);
    }
  }
}

// Round 12
// 437.393 us; speedup vs baseline: 1.4490x; 1.4490x over previous
//
#include <hip/hip_runtime.h>
#include <hip/hip_bf16.h>
#include <math.h>

#define NTOK 4096
#define CH 512
#define CQD 64
#define NBATCH 4

typedef __bf16 bf16x8 __attribute__((ext_vector_type(8)));
typedef float f32x4 __attribute__((ext_vector_type(4)));
typedef unsigned int u32x4 __attribute__((ext_vector_type(4)));
typedef unsigned short u16x4 __attribute__((ext_vector_type(4)));

__device__ __forceinline__ unsigned short f2bf(float f) {
  unsigned int u = __builtin_bit_cast(unsigned int, f);
  unsigned int r = (u + 0x7FFFu + ((u >> 16) & 1u)) >> 16;
  return (unsigned short)r;
}

__device__ __forceinline__ bf16x8 load_frag(const unsigned short* p) {
  u32x4 v = *reinterpret_cast<const u32x4*>(p);
  return __builtin_bit_cast(bf16x8, v);
}

// ---- K0a: transpose + convert x -> xT bf16 (B, N, 1024): [0..511]=xs, [512..1023]=xt
__global__ void k_transpose(const float* __restrict__ xs, const float* __restrict__ xt,
                            unsigned short* __restrict__ xT) {
  __shared__ unsigned short lds[64][66];
  int b = blockIdx.z;
  int n0 = blockIdx.x * 64;
  int c0 = blockIdx.y * 64;  // 0..1023
  const float* src = (c0 < CH) ? xs : xt;
  int cs0 = (c0 < CH) ? c0 : c0 - CH;
  int tid = threadIdx.x;
  int nn = tid & 63, cg = tid >> 6;
  const float* base = src + ((size_t)b * CH + cs0) * NTOK + n0;
  for (int cc = cg; cc < 64; cc += 4)
    lds[cc][nn] = f2bf(base[(size_t)cc * NTOK + nn]);
  __syncthreads();
  int cw = tid & 63, ng = tid >> 6;
  unsigned short* dst = xT + ((size_t)b * NTOK + n0) * 1024 + c0 + cw;
  for (int n2 = ng; n2 < 64; n2 += 4)
    dst[(size_t)n2 * 1024] = lds[cw][n2];
}

// ---- K0b: weights f32 -> bf16 (Wq, Wk, Wv = [Wvs | Wvt])
__global__ void k_weights(const float* __restrict__ Wq, const float* __restrict__ Wk,
                          const float* __restrict__ Wvs, const float* __restrict__ Wvt,
                          unsigned short* __restrict__ wq, unsigned short* __restrict__ wk,
                          unsigned short* __restrict__ wv) {
  int t = blockIdx.x * 256 + threadIdx.x;
  if (t < 32768) {
    wq[t] = f2bf(Wq[t]);
  } else if (t < 65536) {
    int j = t - 32768;
    wk[j] = f2bf(Wk[j]);
  } else {
    int j = t - 65536;
    if (j < 512 * 1024) {
      int c = j >> 10, k = j & 1023;
      float v = (k < 512) ? Wvs[c * 512 + k] : Wvt[c * 512 + (k - 512)];
      wv[j] = f2bf(v);
    }
  }
}

// ---- K1: projection GEMM. D[n][m] = sum_k xT[b][n][koff+k] * W[m][k] (+bias)
// mode 0: out[b][n][m] (N x 64) scalar bf16 stores (for Q, Kt)
// mode 1: out[b][m][n] (C x N) packed 4-wide bf16 stores (for V)
__global__ void __launch_bounds__(256)
k_proj(const unsigned short* __restrict__ xT, const unsigned short* __restrict__ W,
       const float* __restrict__ bias1, const float* __restrict__ bias2,
       unsigned short* __restrict__ out, int Kdim, int koff, int mode) {
  int b = blockIdx.z;
  int n0 = blockIdx.x * 256;
  int m0 = blockIdx.y * 64;
  int tid = threadIdx.x;
  int w = tid >> 6, l = tid & 63;
  int fr = l & 15, fk = l >> 4;
  f32x4 acc[4][4] = {};  // [nstrip][mfrag]
  const unsigned short* xbase =
      xT + ((size_t)b * NTOK + n0 + w * 64 + fr) * 1024 + koff + fk * 8;
  const unsigned short* wbase = W + ((size_t)(m0 + fr)) * Kdim + fk * 8;
  for (int k = 0; k < Kdim; k += 32) {
    bf16x8 a[4], bb[4];
#pragma unroll
    for (int ns = 0; ns < 4; ns++) a[ns] = load_frag(xbase + (size_t)ns * 16 * 1024 + k);
#pragma unroll
    for (int mf = 0; mf < 4; mf++) bb[mf] = load_frag(wbase + (size_t)mf * 16 * Kdim + k);
#pragma unroll
    for (int ns = 0; ns < 4; ns++)
#pragma unroll
      for (int mf = 0; mf < 4; mf++)
        acc[ns][mf] = __builtin_amdgcn_mfma_f32_16x16x32_bf16(a[ns], bb[mf], acc[ns][mf], 0, 0, 0);
  }
  if (mode == 0) {
#pragma unroll
    for (int ns = 0; ns < 4; ns++)
#pragma unroll
      for (int mf = 0; mf < 4; mf++) {
        int m = m0 + mf * 16 + fr;
        float bv = bias1[m];
        int nb = n0 + w * 64 + ns * 16 + fk * 4;
#pragma unroll
        for (int r = 0; r < 4; r++)
          out[((size_t)b * NTOK + nb + r) * CQD + m] = f2bf(acc[ns][mf][r] + bv);
      }
  } else {
#pragma unroll
    for (int ns = 0; ns < 4; ns++)
#pragma unroll
      for (int mf = 0; mf < 4; mf++) {
        int c = m0 + mf * 16 + fr;
        float bv = bias1[c] + bias2[c];
        int nb = n0 + w * 64 + ns * 16 + fk * 4;
        u16x4 pk;
#pragma unroll
        for (int r = 0; r < 4; r++) pk[r] = f2bf(acc[ns][mf][r] + bv);
        *reinterpret_cast<u16x4*>(out + ((size_t)b * CH + c) * NTOK + nb) = pk;
      }
  }
}

// ---- K2a: QK -> P = exp(0.125*S - 8) bf16 [b][i][j] + row sums (atomic).
// Swapped MFMA (R5-verified): A=Kt rows (j), B=Q rows (i); u16x4 j-contiguous stores.
// No LDS, no barriers. Block 256 = 4 waves; wave = 64 i x 64 j.
__global__ void __launch_bounds__(256)
k_qk(const unsigned short* __restrict__ Q, const unsigned short* __restrict__ Kt,
     unsigned short* __restrict__ P, float* __restrict__ rsum) {
  int b = blockIdx.z;
  int i0 = blockIdx.y * 64;
  int w = threadIdx.x >> 6;
  int j0 = blockIdx.x * 256 + w * 64;
  int l = threadIdx.x & 63, fr = l & 15, fk = l >> 4;

  bf16x8 qf[4][2];
#pragma unroll
  for (int f = 0; f < 4; f++) {
    const unsigned short* qb = Q + ((size_t)b * NTOK + i0 + f * 16 + fr) * CQD + fk * 8;
    qf[f][0] = load_frag(qb);
    qf[f][1] = load_frag(qb + 32);
  }
  float dsum[4] = {0.f, 0.f, 0.f, 0.f};
  const unsigned short* kb = Kt + ((size_t)b * NTOK + j0 + fr) * CQD + fk * 8;

#pragma unroll
  for (int jf = 0; jf < 4; jf++) {
    bf16x8 k0 = load_frag(kb + (size_t)jf * 16 * CQD);
    bf16x8 k1 = load_frag(kb + (size_t)jf * 16 * CQD + 32);
#pragma unroll
    for (int f = 0; f < 4; f++) {
      f32x4 s = {};
      s = __builtin_amdgcn_mfma_f32_16x16x32_bf16(k0, qf[f][0], s, 0, 0, 0);
      s = __builtin_amdgcn_mfma_f32_16x16x32_bf16(k1, qf[f][1], s, 0, 0, 0);
      u16x4 pk;
#pragma unroll
      for (int r = 0; r < 4; r++) {
        float p = __expf(0.125f * s[r] - 8.0f);
        dsum[f] += p;
        pk[r] = f2bf(p);
      }
      // i = i0+f*16+fr (D col), j = j0 + jf*16 + fk*4 + r (D row)
      *reinterpret_cast<u16x4*>(P + ((size_t)b * NTOK + i0 + f * 16 + fr) * NTOK + j0 +
                                jf * 16 + fk * 4) = pk;
    }
  }
#pragma unroll
  for (int f = 0; f < 4; f++) {
    float v = dsum[f];
    v += __shfl_xor(v, 16);
    v += __shfl_xor(v, 32);
    if (l < 16) atomicAdd(&rsum[(size_t)b * NTOK + i0 + f * 16 + l], v);
  }
}

// ---- K2b: out[c][i] = (sum_j U[c][j] * P[i][j]) / rsum[i] + xs + xt.
// BM=512: block = 64 i x ALL 512 c (8 waves, wave = 64 c) -> each P row read ONCE
// from HBM (128 MB total, was 652). V is L2-resident via XCD-batch affinity.
// Pure streaming GEMM: no LDS, no barriers; 16 indep b128 loads + 32 MFMA per j-64.
__global__ void __launch_bounds__(512, 2)
k_pv2(const unsigned short* __restrict__ P, const unsigned short* __restrict__ U,
      const float* __restrict__ rsum, const float* __restrict__ xs,
      const float* __restrict__ xt, float* __restrict__ out) {
  int flat = blockIdx.x;          // 256 blocks, 1 per CU
  int xcd = flat & 7;
  int slot = flat >> 3;           // 0..31
  int b = xcd >> 1;               // batch b owns XCDs {2b, 2b+1}
  int i0 = ((slot << 1) | (xcd & 1)) * 64;
  int tid = threadIdx.x;
  int w = tid >> 6;               // wave 0..7
  int l = tid & 63, fr = l & 15, fk = l >> 4;
  int c0 = w * 64;

  f32x4 acc[4][4] = {};  // [is][cf]
  const unsigned short* pbase = P + ((size_t)b * NTOK + i0 + fr) * NTOK + fk * 8;
  const unsigned short* ubase = U + ((size_t)b * CH + c0 + fr) * NTOK + fk * 8;

  for (int j = 0; j < NTOK; j += 64) {
    bf16x8 af[4][2], bf[4][2];
#pragma unroll
    for (int is = 0; is < 4; is++) {
      af[is][0] = load_frag(pbase + (size_t)is * 16 * NTOK + j);
      af[is][1] = load_frag(pbase + (size_t)is * 16 * NTOK + j + 32);
    }
#pragma unroll
    for (int cf = 0; cf < 4; cf++) {
      bf[cf][0] = load_frag(ubase + (size_t)cf * 16 * NTOK + j);
      bf[cf][1] = load_frag(ubase + (size_t)cf * 16 * NTOK + j + 32);
    }
#pragma unroll
    for (int is = 0; is < 4; is++)
#pragma unroll
      for (int cf = 0; cf < 4; cf++) {
        acc[is][cf] = __builtin_amdgcn_mfma_f32_16x16x32_bf16(af[is][0], bf[cf][0],
                                                              acc[is][cf], 0, 0, 0);
        acc[is][cf] = __builtin_amdgcn_mfma_f32_16x16x32_bf16(af[is][1], bf[cf][1],
                                                              acc[is][cf], 0, 0, 0);
      }
  }

  // epilogue: D row = i (is*16+fk*4+r), col = c (cf*16+fr)
  f32x4 rden[4];
#pragma unroll
  for (int is = 0; is < 4; is++) {
    f32x4 rs = *reinterpret_cast<const f32x4*>(rsum + (size_t)b * NTOK + i0 + is * 16 + fk * 4);
#pragma unroll
    for (int r = 0; r < 4; r++) rden[is][r] = 1.0f / rs[r];
  }
#pragma unroll
  for (int is = 0; is < 4; is++)
#pragma unroll
    for (int cf = 0; cf < 4; cf++) {
      int c = c0 + cf * 16 + fr;
      size_t base = ((size_t)b * CH + c) * NTOK + i0 + is * 16 + fk * 4;
      f32x4 r1 = *reinterpret_cast<const f32x4*>(xs + base);
      f32x4 r2 = *reinterpret_cast<const f32x4*>(xt + base);
      f32x4 o;
#pragma unroll
      for (int r = 0; r < 4; r++) o[r] = acc[is][cf][r] * rden[is][r] + r1[r] + r2[r];
      *reinterpret_cast<f32x4*>(out + base) = o;
    }
}

extern "C" void kernel_launch(void* const* d_in, const int* in_sizes, int n_in,
                              void* d_out, int out_size, void* d_ws, size_t ws_size,
                              hipStream_t stream) {
  const float* xs  = (const float*)d_in[0];
  const float* xt  = (const float*)d_in[1];
  const float* Wq  = (const float*)d_in[2];
  const float* bq  = (const float*)d_in[3];
  const float* Wk  = (const float*)d_in[4];
  const float* bk  = (const float*)d_in[5];
  const float* Wvs = (const float*)d_in[6];
  const float* bvs = (const float*)d_in[7];
  const float* Wvt = (const float*)d_in[8];
  const float* bvt = (const float*)d_in[9];
  float* out = (float*)d_out;

  char* ws = (char*)d_ws;
  size_t off = 0;
  unsigned short* xT = (unsigned short*)(ws + off); off += (size_t)NBATCH * NTOK * 1024 * 2;
  unsigned short* wq = (unsigned short*)(ws + off); off += (size_t)64 * 512 * 2;
  unsigned short* wk = (unsigned short*)(ws + off); off += (size_t)64 * 512 * 2;
  unsigned short* wv = (unsigned short*)(ws + off); off += (size_t)512 * 1024 * 2;
  unsigned short* Qb  = (unsigned short*)(ws + off); off += (size_t)NBATCH * NTOK * CQD * 2;
  unsigned short* Ktb = (unsigned short*)(ws + off); off += (size_t)NBATCH * NTOK * CQD * 2;
  unsigned short* Vb  = (unsigned short*)(ws + off); off += (size_t)NBATCH * CH * NTOK * 2;
  float* rsum = (float*)(ws + off); off += (size_t)NBATCH * NTOK * 4;
  unsigned short* P = (unsigned short*)(ws + off);
  size_t p_full = (size_t)NBATCH * NTOK * NTOK * 2;
  if (ws_size < off + p_full) return;  // insufficient scratch: fail safely

  k_transpose<<<dim3(NTOK / 64, 16, NBATCH), 256, 0, stream>>>(xs, xt, xT);
  k_weights<<<dim3(2304), 256, 0, stream>>>(Wq, Wk, Wvs, Wvt, wq, wk, wv);
  k_proj<<<dim3(NTOK / 256, 1, NBATCH), 256, 0, stream>>>(xT, wq, bq, nullptr, Qb, 512, 0, 0);
  k_proj<<<dim3(NTOK / 256, 1, NBATCH), 256, 0, stream>>>(xT, wk, bk, nullptr, Ktb, 512, 512, 0);
  k_proj<<<dim3(NTOK / 256, 8, NBATCH), 256, 0, stream>>>(xT, wv, bvs, bvt, Vb, 1024, 0, 1);
  hipMemsetAsync(rsum, 0, (size_t)NBATCH * NTOK * 4, stream);
  k_qk<<<dim3(NTOK / 256, NTOK / 64, NBATCH), 256, 0, stream>>>(Qb, Ktb, P, rsum);
  k_pv2<<<dim3(256), 512, 0, stream>>>(P, Vb, rsum, xs, xt, out);
}